// Round 13
// baseline (1178.605 us; speedup 1.0000x reference)
//
#include <hip/hip_runtime.h>
#include <hip/hip_bf16.h>

// DGCNN: B=8, P=4096, K=20, H=128.
// EdgeConv: relu([xi, xj-xi]@W + b) == relu(c_i + u_j).
// kNN: gram via 32x32x16 MFMA split-bf16 (3 indep chains hh/hl/lh);
// threshold compaction (tau = exact 20th of 32 distinct window values) ->
// ballot-compact from MFMA C-layout registers -> select 21 rounds dropping
// self, fused with gather/max aggregation.
// R13: dispatch-chain fusion 19 -> 12:
//   selsplit   = select_aggr + bf16 split/swizzle/sqn (layers 1,2)
//   featpart   = feat_mfma + knn_part (shared A-frags)
//   knn3_full  = knn3_part (tau in LDS) + knn3_compact
//   feat3p     = feat3 + pack4;  wprep2 = both weight preps in one launch.
// compact (the plateau kernel) untouched from R11/R12.

static constexpr int B_ = 8, P_ = 4096, K_ = 20, H_ = 128;
static constexpr float FINF = 3.0e38f;
static constexpr int CAPH = 160;  // survivors per row per j-half (E~80)

typedef __attribute__((ext_vector_type(8))) short short8;
typedef __attribute__((ext_vector_type(16))) float floatx16;

__device__ __forceinline__ float dist3(float x0, float x1, float x2,
                                       const float4& v) {
  // MUST be bit-identical between tau and compact phases.
  return fmaf(-2.f, fmaf(x0, v.x, fmaf(x1, v.y, x2 * v.z)), v.w);
}

__device__ __forceinline__ void cvt_split(float v, ushort& h, ushort& l) {
  __hip_bfloat16 hb = __float2bfloat16(v);
  float hf = __bfloat162float(hb);
  __hip_bfloat16 lb = __float2bfloat16(v - hf);
  h = *(ushort*)&hb;
  l = *(ushort*)&lb;
}

// ---------------- layer-1 c/u GEMM (D=3) + pt4 pack ----------------
__global__ __launch_bounds__(256) void feat3p_kernel(
    const float* __restrict__ X, const float* __restrict__ W,
    const float* __restrict__ bias, float* __restrict__ c_out,
    float* __restrict__ u_out, float4* __restrict__ pt4) {
  const int h = threadIdx.x & (H_ - 1);
  const int pg = threadIdx.x >> 7;
  const int bb = blockIdx.x & 7;          // graph -> XCD
  const int pb = blockIdx.x >> 3;
  const int pbase = bb * P_ + pb * 8;
  const int p0 = pbase + pg * 4;
  if (threadIdx.x < 8) {                  // fused pack4 for the 8 points
    const float* row = X + (size_t)(pbase + threadIdx.x) * 3;
    float4 v;
    v.x = row[0]; v.y = row[1]; v.z = row[2];
    v.w = fmaf(v.x, v.x, fmaf(v.y, v.y, v.z * v.z));
    pt4[pbase + threadIdx.x] = v;
  }
  float a0 = 0, a1 = 0, a2 = 0, a3 = 0, u0 = 0, u1 = 0, u2 = 0, u3 = 0;
  const float* xp = X + (size_t)p0 * 3;
#pragma unroll
  for (int d = 0; d < 3; ++d) {
    float wt = W[d * H_ + h];
    float wb = W[(3 + d) * H_ + h];
    float x0 = xp[d], x1 = xp[3 + d], x2 = xp[6 + d], x3 = xp[9 + d];
    a0 = fmaf(x0, wt, a0); u0 = fmaf(x0, wb, u0);
    a1 = fmaf(x1, wt, a1); u1 = fmaf(x1, wb, u1);
    a2 = fmaf(x2, wt, a2); u2 = fmaf(x2, wb, u2);
    a3 = fmaf(x3, wt, a3); u3 = fmaf(x3, wb, u3);
  }
  float bv = bias[h];
  c_out[(size_t)(p0 + 0) * H_ + h] = a0 - u0 + bv;
  c_out[(size_t)(p0 + 1) * H_ + h] = a1 - u1 + bv;
  c_out[(size_t)(p0 + 2) * H_ + h] = a2 - u2 + bv;
  c_out[(size_t)(p0 + 3) * H_ + h] = a3 - u3 + bv;
  u_out[(size_t)(p0 + 0) * H_ + h] = u0;
  u_out[(size_t)(p0 + 1) * H_ + h] = u1;
  u_out[(size_t)(p0 + 2) * H_ + h] = u2;
  u_out[(size_t)(p0 + 3) * H_ + h] = u3;
}

// ===== W prep (both layers): V = [Wt-Wb ; Wb] -> bf16 hi/lo B-frag order ===
__global__ __launch_bounds__(256) void wprep2_kernel(
    const float* __restrict__ W2, const float* __restrict__ W3,
    ushort* __restrict__ Vfh2, ushort* __restrict__ Vfl2,
    ushort* __restrict__ Vfh3, ushort* __restrict__ Vfl3) {
  const int which = blockIdx.x >> 4;  // 0 -> W2, 1 -> W3
  const float* W = which ? W3 : W2;
  ushort* Vfh = which ? Vfh3 : Vfh2;
  ushort* Vfl = which ? Vfl3 : Vfl2;
  int tid = (blockIdx.x & 15) * 256 + threadIdx.x;  // 4096 per weight
  int t = tid >> 9;
  int s = (tid >> 6) & 7;
  int lane = tid & 63;
  int col = t * 32 + (lane & 31);
  int kb = s * 16 + ((lane >> 5) << 3);
  ushort h[8], l[8];
#pragma unroll
  for (int e = 0; e < 8; ++e) {
    int k = kb + e;
    float v;
    if (col < 128) v = W[k * H_ + col] - W[(128 + k) * H_ + col];
    else v = W[(128 + k) * H_ + col - 128];
    cvt_split(v, h[e], l[e]);
  }
  size_t off = (size_t)((t * 8 + s) * 64 + lane) * 8;
  *(short8*)(Vfh + off) = *(short8*)h;
  *(short8*)(Vfl + off) = *(short8*)l;
}

// =============== shared gram machinery (D=128) ===============
__device__ __forceinline__ void stage_async(const ushort* __restrict__ Xhi,
                                            const ushort* __restrict__ Xlo,
                                            size_t tile, char* buf, int w,
                                            int lane) {
  const char* gh = (const char*)(Xhi + tile);
  const char* gl = (const char*)(Xlo + tile);
  const int lo16 = lane * 16;
#pragma unroll
  for (int it = 0; it < 4; ++it) {
    const int off = (w * 4 + it) * 1024;
    __builtin_amdgcn_global_load_lds(
        (const __attribute__((address_space(1))) void*)(gh + off + lo16),
        (__attribute__((address_space(3))) void*)(buf + off), 16, 0, 0);
    __builtin_amdgcn_global_load_lds(
        (const __attribute__((address_space(1))) void*)(gl + off + lo16),
        (__attribute__((address_space(3))) void*)(buf + 16384 + off), 16, 0, 0);
  }
}

__device__ __forceinline__ void stage_async32(const ushort* __restrict__ Xhi,
                                              const ushort* __restrict__ Xlo,
                                              size_t tile, char* buf, int w,
                                              int lane) {
  const char* gh = (const char*)(Xhi + tile);
  const char* gl = (const char*)(Xlo + tile);
  const int lo16 = lane * 16;
#pragma unroll
  for (int it = 0; it < 4; ++it) {
    const int off = (w * 4 + it) * 1024;
    __builtin_amdgcn_global_load_lds(
        (const __attribute__((address_space(1))) void*)(gh + off + lo16),
        (__attribute__((address_space(3))) void*)(buf + off), 16, 0, 0);
    __builtin_amdgcn_global_load_lds(
        (const __attribute__((address_space(1))) void*)(gl + off + lo16),
        (__attribute__((address_space(3))) void*)(buf + 8192 + off), 16, 0, 0);
  }
}

__device__ __forceinline__ void load_afrag_sw(const ushort* __restrict__ X,
                                              size_t gb, int row, int lane,
                                              short8* a) {
  const ushort* base = X + (gb + row) * (size_t)H_;
  const int x = row & 15;
  const int kh = lane >> 5;
#pragma unroll
  for (int s = 0; s < 8; ++s) {
    a[s] = *(const short8*)(base + (((s * 2 + kh) ^ x) << 3));
  }
}

// 32x32 gram tile, 64-j tile layout (lo at +16384). Combine (a0+a1)+a2
// MUST match gram32t exactly.
__device__ __forceinline__ floatx16 gram32(const char* lds, const short8* ahi,
                                           const short8* alo, int jh,
                                           int lane) {
  floatx16 a0, a1, a2;
#pragma unroll
  for (int i = 0; i < 16; ++i) { a0[i] = 0.f; a1[i] = 0.f; a2[i] = 0.f; }
  const int base = (jh * 32 + (lane & 31)) * 256;
  const int kh = lane >> 5;
  const int x = lane & 15;
#pragma unroll
  for (int s = 0; s < 8; ++s) {
    const int off = base + (((s * 2 + kh) ^ x) << 4);
    short8 bh = *(const short8*)(lds + off);
    short8 bl = *(const short8*)(lds + 16384 + off);
    a0 = __builtin_amdgcn_mfma_f32_32x32x16_bf16(ahi[s], bh, a0, 0, 0, 0);
    a1 = __builtin_amdgcn_mfma_f32_32x32x16_bf16(ahi[s], bl, a1, 0, 0, 0);
    a2 = __builtin_amdgcn_mfma_f32_32x32x16_bf16(alo[s], bh, a2, 0, 0, 0);
  }
  floatx16 acc;
#pragma unroll
  for (int i = 0; i < 16; ++i) acc[i] = (a0[i] + a1[i]) + a2[i];
  return acc;
}

// 32x32 gram tile, 32-j tile layout (lo at +8192). Same value-order.
__device__ __forceinline__ floatx16 gram32t(const char* lds, const short8* ahi,
                                            const short8* alo, int lane) {
  floatx16 a0, a1, a2;
#pragma unroll
  for (int i = 0; i < 16; ++i) { a0[i] = 0.f; a1[i] = 0.f; a2[i] = 0.f; }
  const int base = (lane & 31) * 256;
  const int kh = lane >> 5;
  const int x = lane & 15;
#pragma unroll
  for (int s = 0; s < 8; ++s) {
    const int off = base + (((s * 2 + kh) ^ x) << 4);
    short8 bh = *(const short8*)(lds + off);
    short8 bl = *(const short8*)(lds + 8192 + off);
    a0 = __builtin_amdgcn_mfma_f32_32x32x16_bf16(ahi[s], bh, a0, 0, 0, 0);
    a1 = __builtin_amdgcn_mfma_f32_32x32x16_bf16(ahi[s], bl, a1, 0, 0, 0);
    a2 = __builtin_amdgcn_mfma_f32_32x32x16_bf16(alo[s], bh, a2, 0, 0, 0);
  }
  floatx16 acc;
#pragma unroll
  for (int i = 0; i < 16; ++i) acc[i] = (a0[i] + a1[i]) + a2[i];
  return acc;
}

// exact 20th-smallest of 32 register values (serial extract, static idx)
__device__ __forceinline__ float kth20_of32(float* v) {
  float m = 0.f;
  for (int sel = 0; sel < K_; ++sel) {
    m = v[0];
#pragma unroll
    for (int t = 1; t < 32; ++t) m = fminf(m, v[t]);
    bool done = false;
#pragma unroll
    for (int t = 0; t < 32; ++t) {
      if (!done && v[t] == m) { v[t] = FINF; done = true; }
    }
  }
  return m;
}

// ===== featpart: feat GEMM (MFMA) + knn part/tau, shared A-frags ==========
// grid B*64 (XCD-swizzled); 256 thr = 4 waves (rh = w>>1, jh = w&1).
__global__ __launch_bounds__(256) void featpart_kernel(
    const ushort* __restrict__ Xhi, const ushort* __restrict__ Xlo,
    const ushort* __restrict__ Vfh, const ushort* __restrict__ Vfl,
    const float* __restrict__ bias, float* __restrict__ c_out,
    float* __restrict__ u_out, const float* __restrict__ sqn,
    float* __restrict__ tau) {
  __shared__ char buf[32768];        // single-buffer async staging
  __shared__ float ldist[64 * 65];   // dist tile / top-8 dump

  const int tid = threadIdx.x;
  const int lane = tid & 63;
  const int w = tid >> 6;
  const int rh = w >> 1, jh = w & 1;
  const int b = blockIdx.x & 7;      // graph -> XCD
  const int i0 = (blockIdx.x >> 3) * 64;
  const size_t gb = (size_t)b * P_;

  short8 ahi[8], alo[8];
  const int arow = i0 + rh * 32 + (lane & 31);
  load_afrag_sw(Xhi, gb, arow, lane, ahi);
  load_afrag_sw(Xlo, gb, arow, lane, alo);

  // ---- feat phase: wave (rh,jh) -> rows rh*32.., col-tiles jh*4+tt ----
  const int rl = 4 * (lane >> 5);
#pragma unroll
  for (int tt = 0; tt < 4; ++tt) {
    const int t = jh * 4 + tt;       // 0..7
    floatx16 a0, a1, a2;
#pragma unroll
    for (int i = 0; i < 16; ++i) { a0[i] = 0.f; a1[i] = 0.f; a2[i] = 0.f; }
#pragma unroll
    for (int s = 0; s < 8; ++s) {
      const size_t off = (size_t)((t * 8 + s) * 64 + lane) * 8;
      short8 bh = *(const short8*)(Vfh + off);
      short8 bl = *(const short8*)(Vfl + off);
      a0 = __builtin_amdgcn_mfma_f32_32x32x16_bf16(ahi[s], bh, a0, 0, 0, 0);
      a1 = __builtin_amdgcn_mfma_f32_32x32x16_bf16(ahi[s], bl, a1, 0, 0, 0);
      a2 = __builtin_amdgcn_mfma_f32_32x32x16_bf16(alo[s], bh, a2, 0, 0, 0);
    }
    const int col = t * 32 + (lane & 31);
    if (jh == 0) {
      float bv = bias[col];
#pragma unroll
      for (int g = 0; g < 16; ++g) {
        int row = i0 + rh * 32 + rl + (g & 3) + 8 * (g >> 2);
        c_out[(gb + row) * (size_t)H_ + col] = ((a0[g] + a1[g]) + a2[g]) + bv;
      }
    } else {
#pragma unroll
      for (int g = 0; g < 16; ++g) {
        int row = i0 + rh * 32 + rl + (g & 3) + 8 * (g >> 2);
        u_out[(gb + row) * (size_t)H_ + col - 128] = (a0[g] + a1[g]) + a2[g];
      }
    }
  }

  // ---- part phase: window [0,512) -> tau (unchanged arithmetic) ----
  const int rowb = rh * 32 + rl;
  const int jcol = jh * 32 + (lane & 31);
  const int srow = tid >> 2;
  const int sr = tid & 3;
  const int gi = i0 + srow;
  float bd[8];
#pragma unroll
  for (int k = 0; k < 8; ++k) bd[k] = FINF;
  float worst = FINF;

  for (int ch = 0; ch < 8; ++ch) {
    const int tb = ch * 64;
    stage_async(Xhi, Xlo, (gb + tb) * (size_t)H_, buf, w, lane);
    float sqv = sqn[gb + tb + jcol];
    __syncthreads();                    // drain async loads
    floatx16 acc = gram32(buf, ahi, alo, jh, lane);
#pragma unroll
    for (int g = 0; g < 16; ++g) {
      ldist[(rowb + (g & 3) + 8 * (g >> 2)) * 65 + jcol] =
          fmaf(-2.f, acc[g], sqv);
    }
    __syncthreads();                    // dist ready; tile reads done
    const float* drow = ldist + srow * 65 + sr * 16;
#pragma unroll 4
    for (int jj = 0; jj < 16; ++jj) {
      float s = drow[jj];
      int jg = tb + sr * 16 + jj;
      if (s < worst && jg != gi) {       // tau must exclude self
        bool done = false;
#pragma unroll
        for (int k = 0; k < 8; ++k) {
          if (!done && bd[k] == worst) { bd[k] = s; done = true; }
        }
        worst = bd[0];
#pragma unroll
        for (int k = 1; k < 8; ++k) worst = fmaxf(worst, bd[k]);
      }
    }
  }
  __syncthreads();
#pragma unroll
  for (int k = 0; k < 8; ++k) ldist[srow * 65 + sr * 8 + k] = bd[k];
  __syncthreads();
  if (sr == 0) {
    float v[32];
#pragma unroll
    for (int t = 0; t < 32; ++t) v[t] = ldist[srow * 65 + t];
    tau[gb + gi] = kth20_of32(v);
  }
}

// ==== D=128 compact: dbuf halves, XCD-swizzled (UNCHANGED from R11) ====
__global__ __launch_bounds__(128) void knn_compact_kernel(
    const ushort* __restrict__ Xhi, const ushort* __restrict__ Xlo,
    const float* __restrict__ sqn, const float* __restrict__ tau,
    float2* __restrict__ cand, int* __restrict__ cnt) {
  __shared__ char buf[2][16384];  // 32 KB double-buffered staging

  const int tid = threadIdx.x;
  const int lane = tid & 63;
  const int w = tid >> 6;         // wave = row-half
  const int b = blockIdx.x & 7;   // graph -> XCD
  const int rest = blockIdx.x >> 3;
  const int half = rest & 1;
  const int i0 = (rest >> 1) * 64;
  const size_t gb = (size_t)b * P_;

  short8 ahi[8], alo[8];
  const int arow = i0 + w * 32 + (lane & 31);
  load_afrag_sw(Xhi, gb, arow, lane, ahi);
  load_afrag_sw(Xlo, gb, arow, lane, alo);

  const int rowb = i0 + w * 32 + 4 * (lane >> 5);
  float taur[16];
  int cur[16];
#pragma unroll
  for (int g = 0; g < 16; ++g) {
    taur[g] = tau[gb + rowb + (g & 3) + 8 * (g >> 2)];
    cur[g] = 0;
  }
  float2* candrow = cand + (gb + rowb) * (size_t)(2 * CAPH) + half * CAPH;
  const unsigned lmask = (1u << (lane & 31)) - 1u;
  const int jbase = half * 2048;

  stage_async32(Xhi, Xlo, (gb + jbase) * (size_t)H_, buf[0], w, lane);
  float sqv_next = sqn[gb + jbase + (lane & 31)];

  for (int c = 0; c < 64; ++c) {
    const int tb = jbase + c * 32;
    __syncthreads();          // buf[c&1] staged; prior reads of other buf done
    float sqv = sqv_next;
    if (c < 63) {             // prefetch next tile; overlaps gram below
      stage_async32(Xhi, Xlo, (gb + tb + 32) * (size_t)H_, buf[(c + 1) & 1], w,
                    lane);
      sqv_next = sqn[gb + tb + 32 + (lane & 31)];
    }
    floatx16 acc = gram32t(buf[c & 1], ahi, alo, lane);
    const int jg = tb + (lane & 31);
#pragma unroll
    for (int g = 0; g < 16; ++g) {
      float d = fmaf(-2.f, acc[g], sqv);
      bool pred = (d <= taur[g]);
      unsigned long long mk = __ballot(pred);
      if (mk) {
        unsigned seg = (lane >= 32) ? (unsigned)(mk >> 32) : (unsigned)mk;
        int idx = cur[g] + __popc(seg & lmask);
        if (pred && idx < CAPH) {
          float2 e;
          e.x = d;
          e.y = __int_as_float(jg);
          candrow[(size_t)((g & 3) + 8 * (g >> 2)) * (2 * CAPH) + idx] = e;
        }
        cur[g] += __popc(seg);
      }
    }
  }
  if ((lane & 31) == 0) {
#pragma unroll
    for (int g = 0; g < 16; ++g) {
      int row = rowb + (g & 3) + 8 * (g >> 2);
      cnt[(gb + row) * 2 + half] = cur[g] < CAPH ? cur[g] : CAPH;
    }
  }
}

// ===== knn3_full: tau (part) in LDS + compact, one kernel (D=3) =====
// grid B*64*2 (XCD-swizzled); part phase redundant across the 2 halves.
__global__ __launch_bounds__(256) void knn3_full_kernel(
    const float4* __restrict__ pt4, float2* __restrict__ cand,
    int* __restrict__ cnt) {
  __shared__ float lv[64 * 33];
  __shared__ float ltau[64];
  const int tid = threadIdx.x;
  const int b = blockIdx.x & 7;      // graph -> XCD
  const int rest = blockIdx.x >> 3;
  const int half = rest & 1;
  const int i0 = (rest >> 1) * 64;
  const size_t gb = (size_t)b * P_;

  // ---- part/tau phase: window [0,1024), 4 splits of 256 ----
  {
    const int row_local = tid >> 2;
    const int r = tid & 3;
    const int gi = i0 + row_local;
    float4 pi = pt4[gb + gi];
    float bd[8];
#pragma unroll
    for (int k = 0; k < 8; ++k) bd[k] = FINF;
    float worst = FINF;
    const float4* pg = pt4 + gb + r * 256;
#pragma unroll 4
    for (int jj = 0; jj < 256; ++jj) {
      float4 v = pg[jj];
      float d = dist3(pi.x, pi.y, pi.z, v);
      int jg = r * 256 + jj;
      if (d < worst && jg != gi) {       // tau must exclude self
        bool done = false;
#pragma unroll
        for (int k = 0; k < 8; ++k) {
          if (!done && bd[k] == worst) { bd[k] = d; done = true; }
        }
        worst = bd[0];
#pragma unroll
        for (int k = 1; k < 8; ++k) worst = fmaxf(worst, bd[k]);
      }
    }
#pragma unroll
    for (int k = 0; k < 8; ++k) lv[row_local * 33 + r * 8 + k] = bd[k];
    __syncthreads();
    if (r == 0) {
      float v[32];
#pragma unroll
      for (int t = 0; t < 32; ++t) v[t] = lv[row_local * 33 + t];
      ltau[row_local] = kth20_of32(v);
    }
  }
  __syncthreads();

  // ---- compact phase (identical arithmetic to R11 knn3_compact) ----
  const int lane = tid & 63;
  const int w = tid >> 6;
  const int r0 = i0 + w * 16;
  float xr0[16], xr1[16], xr2[16], taur[16];
  int cur[16];
#pragma unroll
  for (int r = 0; r < 16; ++r) {
    float4 p = pt4[gb + r0 + r];
    xr0[r] = p.x; xr1[r] = p.y; xr2[r] = p.z;
    taur[r] = ltau[w * 16 + r];
    cur[r] = 0;
  }
  const float4* pg = pt4 + gb + half * 2048;
  for (int ch = 0; ch < 32; ++ch) {
    float4 v = pg[ch * 64 + lane];
    int jg = half * 2048 + ch * 64 + lane;
#pragma unroll
    for (int r = 0; r < 16; ++r) {
      float d = dist3(xr0[r], xr1[r], xr2[r], v);
      bool pred = (d <= taur[r]);
      unsigned long long mk = __ballot(pred);
      if (mk) {
        int n = __popcll(mk);
        int pre = __popcll(mk & ((1ull << lane) - 1ull));
        int idx = cur[r] + pre;
        if (pred && idx < CAPH) {
          float2 e;
          e.x = d;
          e.y = __int_as_float(jg);
          cand[(gb + r0 + r) * (size_t)(2 * CAPH) + half * CAPH + idx] = e;
        }
        cur[r] += n;
      }
    }
  }
  if (lane == 0) {
#pragma unroll
    for (int r = 0; r < 16; ++r)
      cnt[(gb + r0 + r) * 2 + half] = cur[r] < CAPH ? cur[r] : CAPH;
  }
}

// ===== selsplit: select top-21 (drop self) + gather/max aggr + optional
//       f32 out + optional bf16 split/swizzle/sqn for the next layer =====
__global__ __launch_bounds__(256) void selsplit_kernel(
    const float2* __restrict__ cand, const int* __restrict__ cnt,
    const float* __restrict__ c, const float* __restrict__ u,
    float* __restrict__ out, ushort* __restrict__ hi,
    ushort* __restrict__ lo, float* __restrict__ sqn) {
  __shared__ int ljs[4][24];
  __shared__ float aggv[4][128];
  const int w = threadIdx.x >> 6;
  const int lane = threadIdx.x & 63;
  const int b = blockIdx.x & 7;      // graph -> XCD
  const int rowbase = b * P_ + (blockIdx.x >> 3) * 4;
  const int row = rowbase + w;
  const int c0 = cnt[row * 2], c1 = cnt[row * 2 + 1];
  const int ctot = c0 + c1;
  float d[5];
  int j[5];
#pragma unroll
  for (int s = 0; s < 5; ++s) {
    int m = s * 64 + lane;
    bool valid = m < ctot;
    int addr = (m < c0) ? m : (CAPH + m - c0);
    if (!valid) addr = 0;
    float2 e = cand[(size_t)row * (2 * CAPH) + addr];
    d[s] = valid ? e.x : FINF;
    j[s] = __float_as_int(e.y);
  }
  for (int round = 0; round < K_ + 1; ++round) {
    float bm = d[0];
    int bs = 0;
#pragma unroll
    for (int s = 1; s < 5; ++s) {
      if (d[s] < bm) { bm = d[s]; bs = s; }
    }
    int id = (lane << 3) | bs;
#pragma unroll
    for (int off = 1; off < 64; off <<= 1) {
      float od = __shfl_xor(bm, off);
      int oid = __shfl_xor(id, off);
      if (od < bm || (od == bm && oid < id)) { bm = od; id = oid; }
    }
    int owner = id >> 3, os = id & 7;
    if (lane == owner) {
      int jv = 0;
#pragma unroll
      for (int s = 0; s < 5; ++s) {
        if (s == os) { jv = j[s]; d[s] = FINF; }
      }
      ljs[w][round] = jv;
    }
  }
  // ---- aggregation: h split 2 per lane; rounds 1..20 are the neighbors
  const float2* c2p = (const float2*)(c + (size_t)row * H_);
  float2 ci = c2p[lane];
  float mx = 0.f, my = 0.f;  // relu floor
#pragma unroll 4
  for (int k = 1; k <= K_; ++k) {
    int jj = ljs[w][k];
    float2 uv = *(const float2*)(u + ((size_t)(b << 12) + jj) * H_ + lane * 2);
    mx = fmaxf(mx, ci.x + uv.x);
    my = fmaxf(my, ci.y + uv.y);
  }
  if (out != nullptr) {
    float2 o;
    o.x = mx; o.y = my;
    *(float2*)(out + (size_t)row * H_ + lane * 2) = o;
  }
  if (hi != nullptr) {
    aggv[w][lane * 2] = mx;
    aggv[w][lane * 2 + 1] = my;
    __syncthreads();
    const int tid = threadIdx.x;
    if (tid < 64) {
      const int r = tid >> 4, m = tid & 15;
      const int rrow = rowbase + r;
      float vv[8];
      float ss = 0.f;
      ushort hh[8], ll[8];
#pragma unroll
      for (int e = 0; e < 8; ++e) {
        vv[e] = aggv[r][m * 8 + e];
        ss = fmaf(vv[e], vv[e], ss);
        cvt_split(vv[e], hh[e], ll[e]);
      }
      size_t dst = ((size_t)rrow << 7) + ((size_t)(m ^ (rrow & 15)) << 3);
      *(short8*)(hi + dst) = *(short8*)hh;
      *(short8*)(lo + dst) = *(short8*)ll;
#pragma unroll
      for (int off = 1; off < 16; off <<= 1) ss += __shfl_xor(ss, off);
      if (m == 0) sqn[rrow] = ss;
    }
  }
}

// ---------------- head: mean pool (partials) + MLP ----------------
__global__ __launch_bounds__(128) void pool_kernel(const float* __restrict__ hf,
                                                   float* __restrict__ psum) {
  constexpr int CHUNK = 64;
  int blk = blockIdx.x;       // B_*64
  int b = blk >> 6;
  int chunk = blk & 63;
  int h = threadIdx.x;
  int base = (b << 12) + chunk * CHUNK;
  float acc = 0.f;
#pragma unroll 4
  for (int p = 0; p < CHUNK; ++p) acc += hf[(size_t)(base + p) * H_ + h];
  psum[blk * H_ + h] = acc;
}

__global__ __launch_bounds__(128) void head_kernel(
    const float* __restrict__ psum, const float* __restrict__ W4,
    const float* __restrict__ b4, const float* __restrict__ W5,
    const float* __restrict__ b5, float* __restrict__ out) {
  int b = blockIdx.x, h = threadIdx.x;
  __shared__ float g[H_];
  __shared__ float t[H_];
  float s = 0.f;
#pragma unroll 4
  for (int ch = 0; ch < 64; ++ch) s += psum[(b * 64 + ch) * H_ + h];
  g[h] = s * (1.0f / P_);
  __syncthreads();
  float acc = b4[h];
#pragma unroll 4
  for (int d = 0; d < H_; ++d) acc = fmaf(g[d], W4[d * H_ + h], acc);
  t[h] = fmaxf(acc, 0.f);
  __syncthreads();
  if (h < 3) {
    float o = b5[h];
#pragma unroll 4
    for (int d = 0; d < H_; ++d) o = fmaf(t[d], W5[d * 3 + h], o);
    out[b * 3 + h] = o;
  }
}

extern "C" void kernel_launch(void* const* d_in, const int* in_sizes, int n_in,
                              void* d_out, int out_size, void* d_ws,
                              size_t ws_size, hipStream_t stream) {
  const float* x  = (const float*)d_in[0];
  const float* W1 = (const float*)d_in[1];
  const float* b1 = (const float*)d_in[2];
  const float* W2 = (const float*)d_in[3];
  const float* b2 = (const float*)d_in[4];
  const float* W3 = (const float*)d_in[5];
  const float* b3 = (const float*)d_in[6];
  const float* W4 = (const float*)d_in[7];
  const float* b4 = (const float*)d_in[8];
  const float* W5 = (const float*)d_in[9];
  const float* b5 = (const float*)d_in[10];
  float* out = (float*)d_out;

  char* ws = (char*)d_ws;
  const size_t NF = (size_t)B_ * P_ * H_;   // 4,194,304
  const size_t NP_ = (size_t)B_ * P_;       // 32768
  float*  bufA = (float*)ws;  ws += NF * 4;
  float*  bufB = (float*)ws;  ws += NF * 4;
  float*  bufU = (float*)ws;  ws += NF * 4;
  ushort* xhi  = (ushort*)ws; ws += NF * 2;
  ushort* xlo  = (ushort*)ws; ws += NF * 2;
  float*  sqn  = (float*)ws;  ws += NP_ * 4;
  float*  psum = (float*)ws;  ws += (size_t)B_ * 64 * H_ * 4;
  float*  tau  = (float*)ws;  ws += NP_ * 4;
  int*    cnt  = (int*)ws;    ws += NP_ * 2 * 4;
  float4* pt4  = (float4*)ws; ws += NP_ * 16;
  ushort* vfh2 = (ushort*)ws; ws += 32768 * 2;
  ushort* vfl2 = (ushort*)ws; ws += 32768 * 2;
  ushort* vfh3 = (ushort*)ws; ws += 32768 * 2;
  ushort* vfl3 = (ushort*)ws; ws += 32768 * 2;
  float2* cand = (float2*)ws; ws += NP_ * (size_t)(2 * CAPH) * 8;

  const int NP = B_ * P_;
  dim3 blk256(256), blk128(128);

  // ---- weight prep for layers 2+3 (no deps on pipeline)
  wprep2_kernel<<<32, blk256, 0, stream>>>(W2, W3, vfh2, vfl2, vfh3, vfl3);

  // ---- layer 1 (D=3)
  feat3p_kernel<<<NP / 8, blk256, 0, stream>>>(x, W1, b1, bufA, bufU, pt4);
  knn3_full_kernel<<<B_ * 64 * 2, blk256, 0, stream>>>(pt4, cand, cnt);
  selsplit_kernel<<<NP / 4, blk256, 0, stream>>>(cand, cnt, bufA, bufU,
                                                 nullptr, xhi, xlo, sqn);

  // ---- layer 2 (D=128)
  featpart_kernel<<<B_ * 64, blk256, 0, stream>>>(xhi, xlo, vfh2, vfl2, b2,
                                                  bufB, bufU, sqn, tau);
  knn_compact_kernel<<<B_ * 64 * 2, blk128, 0, stream>>>(xhi, xlo, sqn, tau,
                                                         cand, cnt);
  selsplit_kernel<<<NP / 4, blk256, 0, stream>>>(cand, cnt, bufB, bufU,
                                                 nullptr, xhi, xlo, sqn);

  // ---- layer 3 (D=128)
  featpart_kernel<<<B_ * 64, blk256, 0, stream>>>(xhi, xlo, vfh3, vfl3, b3,
                                                  bufB, bufU, sqn, tau);
  knn_compact_kernel<<<B_ * 64 * 2, blk128, 0, stream>>>(xhi, xlo, sqn, tau,
                                                         cand, cnt);
  selsplit_kernel<<<NP / 4, blk256, 0, stream>>>(cand, cnt, bufB, bufU,
                                                 bufA, nullptr, nullptr,
                                                 nullptr);

  // ---- head
  pool_kernel<<<B_ * 64, blk128, 0, stream>>>(bufA, psum);
  head_kernel<<<B_, blk128, 0, stream>>>(psum, W4, b4, W5, b5, out);
}

// Round 14
// 1068.420 us; speedup vs baseline: 1.1031x; 1.1031x over previous
//
#include <hip/hip_runtime.h>
#include <hip/hip_bf16.h>

// DGCNN: B=8, P=4096, K=20, H=128.
// EdgeConv: relu([xi, xj-xi]@W + b) == relu(c_i + u_j).
// kNN: gram via 32x32x16 MFMA split-bf16 (3 indep chains hh/hl/lh);
// threshold compaction -> ballot-compact from MFMA C-layout registers ->
// select 21 rounds dropping self, fused with gather/max aggregation.
// R14: tau via BUCKET MINIMA (branch-free): 20th-smallest of >=20 disjoint
//      bucket minima (self excluded) >= true 20th-excluding-self. Kills the
//      serial top-8 insert chains in both part phases (D=3 was ~300 us).
//      CAPH 160->192, select 6 slots. Rest identical to R13.

static constexpr int B_ = 8, P_ = 4096, K_ = 20, H_ = 128;
static constexpr float FINF = 3.0e38f;
static constexpr int CAPH = 192;  // survivors per row per j-half (E~116 D=128)

typedef __attribute__((ext_vector_type(8))) short short8;
typedef __attribute__((ext_vector_type(16))) float floatx16;

__device__ __forceinline__ float dist3(float x0, float x1, float x2,
                                       const float4& v) {
  // MUST be bit-identical between tau and compact phases.
  return fmaf(-2.f, fmaf(x0, v.x, fmaf(x1, v.y, x2 * v.z)), v.w);
}

__device__ __forceinline__ void cvt_split(float v, ushort& h, ushort& l) {
  __hip_bfloat16 hb = __float2bfloat16(v);
  float hf = __bfloat162float(hb);
  __hip_bfloat16 lb = __float2bfloat16(v - hf);
  h = *(ushort*)&hb;
  l = *(ushort*)&lb;
}

// ---------------- layer-1 c/u GEMM (D=3) + pt4 pack ----------------
__global__ __launch_bounds__(256) void feat3p_kernel(
    const float* __restrict__ X, const float* __restrict__ W,
    const float* __restrict__ bias, float* __restrict__ c_out,
    float* __restrict__ u_out, float4* __restrict__ pt4) {
  const int h = threadIdx.x & (H_ - 1);
  const int pg = threadIdx.x >> 7;
  const int bb = blockIdx.x & 7;          // graph -> XCD
  const int pb = blockIdx.x >> 3;
  const int pbase = bb * P_ + pb * 8;
  const int p0 = pbase + pg * 4;
  if (threadIdx.x < 8) {                  // fused pack4 for the 8 points
    const float* row = X + (size_t)(pbase + threadIdx.x) * 3;
    float4 v;
    v.x = row[0]; v.y = row[1]; v.z = row[2];
    v.w = fmaf(v.x, v.x, fmaf(v.y, v.y, v.z * v.z));
    pt4[pbase + threadIdx.x] = v;
  }
  float a0 = 0, a1 = 0, a2 = 0, a3 = 0, u0 = 0, u1 = 0, u2 = 0, u3 = 0;
  const float* xp = X + (size_t)p0 * 3;
#pragma unroll
  for (int d = 0; d < 3; ++d) {
    float wt = W[d * H_ + h];
    float wb = W[(3 + d) * H_ + h];
    float x0 = xp[d], x1 = xp[3 + d], x2 = xp[6 + d], x3 = xp[9 + d];
    a0 = fmaf(x0, wt, a0); u0 = fmaf(x0, wb, u0);
    a1 = fmaf(x1, wt, a1); u1 = fmaf(x1, wb, u1);
    a2 = fmaf(x2, wt, a2); u2 = fmaf(x2, wb, u2);
    a3 = fmaf(x3, wt, a3); u3 = fmaf(x3, wb, u3);
  }
  float bv = bias[h];
  c_out[(size_t)(p0 + 0) * H_ + h] = a0 - u0 + bv;
  c_out[(size_t)(p0 + 1) * H_ + h] = a1 - u1 + bv;
  c_out[(size_t)(p0 + 2) * H_ + h] = a2 - u2 + bv;
  c_out[(size_t)(p0 + 3) * H_ + h] = a3 - u3 + bv;
  u_out[(size_t)(p0 + 0) * H_ + h] = u0;
  u_out[(size_t)(p0 + 1) * H_ + h] = u1;
  u_out[(size_t)(p0 + 2) * H_ + h] = u2;
  u_out[(size_t)(p0 + 3) * H_ + h] = u3;
}

// ===== W prep (both layers): V = [Wt-Wb ; Wb] -> bf16 hi/lo B-frag order ===
__global__ __launch_bounds__(256) void wprep2_kernel(
    const float* __restrict__ W2, const float* __restrict__ W3,
    ushort* __restrict__ Vfh2, ushort* __restrict__ Vfl2,
    ushort* __restrict__ Vfh3, ushort* __restrict__ Vfl3) {
  const int which = blockIdx.x >> 4;  // 0 -> W2, 1 -> W3
  const float* W = which ? W3 : W2;
  ushort* Vfh = which ? Vfh3 : Vfh2;
  ushort* Vfl = which ? Vfl3 : Vfl2;
  int tid = (blockIdx.x & 15) * 256 + threadIdx.x;  // 4096 per weight
  int t = tid >> 9;
  int s = (tid >> 6) & 7;
  int lane = tid & 63;
  int col = t * 32 + (lane & 31);
  int kb = s * 16 + ((lane >> 5) << 3);
  ushort h[8], l[8];
#pragma unroll
  for (int e = 0; e < 8; ++e) {
    int k = kb + e;
    float v;
    if (col < 128) v = W[k * H_ + col] - W[(128 + k) * H_ + col];
    else v = W[(128 + k) * H_ + col - 128];
    cvt_split(v, h[e], l[e]);
  }
  size_t off = (size_t)((t * 8 + s) * 64 + lane) * 8;
  *(short8*)(Vfh + off) = *(short8*)h;
  *(short8*)(Vfl + off) = *(short8*)l;
}

// =============== shared gram machinery (D=128) ===============
__device__ __forceinline__ void stage_async(const ushort* __restrict__ Xhi,
                                            const ushort* __restrict__ Xlo,
                                            size_t tile, char* buf, int w,
                                            int lane) {
  const char* gh = (const char*)(Xhi + tile);
  const char* gl = (const char*)(Xlo + tile);
  const int lo16 = lane * 16;
#pragma unroll
  for (int it = 0; it < 4; ++it) {
    const int off = (w * 4 + it) * 1024;
    __builtin_amdgcn_global_load_lds(
        (const __attribute__((address_space(1))) void*)(gh + off + lo16),
        (__attribute__((address_space(3))) void*)(buf + off), 16, 0, 0);
    __builtin_amdgcn_global_load_lds(
        (const __attribute__((address_space(1))) void*)(gl + off + lo16),
        (__attribute__((address_space(3))) void*)(buf + 16384 + off), 16, 0, 0);
  }
}

__device__ __forceinline__ void stage_async32(const ushort* __restrict__ Xhi,
                                              const ushort* __restrict__ Xlo,
                                              size_t tile, char* buf, int w,
                                              int lane) {
  const char* gh = (const char*)(Xhi + tile);
  const char* gl = (const char*)(Xlo + tile);
  const int lo16 = lane * 16;
#pragma unroll
  for (int it = 0; it < 4; ++it) {
    const int off = (w * 4 + it) * 1024;
    __builtin_amdgcn_global_load_lds(
        (const __attribute__((address_space(1))) void*)(gh + off + lo16),
        (__attribute__((address_space(3))) void*)(buf + off), 16, 0, 0);
    __builtin_amdgcn_global_load_lds(
        (const __attribute__((address_space(1))) void*)(gl + off + lo16),
        (__attribute__((address_space(3))) void*)(buf + 8192 + off), 16, 0, 0);
  }
}

__device__ __forceinline__ void load_afrag_sw(const ushort* __restrict__ X,
                                              size_t gb, int row, int lane,
                                              short8* a) {
  const ushort* base = X + (gb + row) * (size_t)H_;
  const int x = row & 15;
  const int kh = lane >> 5;
#pragma unroll
  for (int s = 0; s < 8; ++s) {
    a[s] = *(const short8*)(base + (((s * 2 + kh) ^ x) << 3));
  }
}

// 32x32 gram tile, 64-j tile layout (lo at +16384). Combine (a0+a1)+a2
// MUST match gram32t exactly.
__device__ __forceinline__ floatx16 gram32(const char* lds, const short8* ahi,
                                           const short8* alo, int jh,
                                           int lane) {
  floatx16 a0, a1, a2;
#pragma unroll
  for (int i = 0; i < 16; ++i) { a0[i] = 0.f; a1[i] = 0.f; a2[i] = 0.f; }
  const int base = (jh * 32 + (lane & 31)) * 256;
  const int kh = lane >> 5;
  const int x = lane & 15;
#pragma unroll
  for (int s = 0; s < 8; ++s) {
    const int off = base + (((s * 2 + kh) ^ x) << 4);
    short8 bh = *(const short8*)(lds + off);
    short8 bl = *(const short8*)(lds + 16384 + off);
    a0 = __builtin_amdgcn_mfma_f32_32x32x16_bf16(ahi[s], bh, a0, 0, 0, 0);
    a1 = __builtin_amdgcn_mfma_f32_32x32x16_bf16(ahi[s], bl, a1, 0, 0, 0);
    a2 = __builtin_amdgcn_mfma_f32_32x32x16_bf16(alo[s], bh, a2, 0, 0, 0);
  }
  floatx16 acc;
#pragma unroll
  for (int i = 0; i < 16; ++i) acc[i] = (a0[i] + a1[i]) + a2[i];
  return acc;
}

// 32x32 gram tile, 32-j tile layout (lo at +8192). Same value-order.
__device__ __forceinline__ floatx16 gram32t(const char* lds, const short8* ahi,
                                            const short8* alo, int lane) {
  floatx16 a0, a1, a2;
#pragma unroll
  for (int i = 0; i < 16; ++i) { a0[i] = 0.f; a1[i] = 0.f; a2[i] = 0.f; }
  const int base = (lane & 31) * 256;
  const int kh = lane >> 5;
  const int x = lane & 15;
#pragma unroll
  for (int s = 0; s < 8; ++s) {
    const int off = base + (((s * 2 + kh) ^ x) << 4);
    short8 bh = *(const short8*)(lds + off);
    short8 bl = *(const short8*)(lds + 8192 + off);
    a0 = __builtin_amdgcn_mfma_f32_32x32x16_bf16(ahi[s], bh, a0, 0, 0, 0);
    a1 = __builtin_amdgcn_mfma_f32_32x32x16_bf16(ahi[s], bl, a1, 0, 0, 0);
    a2 = __builtin_amdgcn_mfma_f32_32x32x16_bf16(alo[s], bh, a2, 0, 0, 0);
  }
  floatx16 acc;
#pragma unroll
  for (int i = 0; i < 16; ++i) acc[i] = (a0[i] + a1[i]) + a2[i];
  return acc;
}

// exact 20th-smallest of 32 register values (serial extract, static idx)
__device__ __forceinline__ float kth20_of32(float* v) {
  float m = 0.f;
  for (int sel = 0; sel < K_; ++sel) {
    m = v[0];
#pragma unroll
    for (int t = 1; t < 32; ++t) m = fminf(m, v[t]);
    bool done = false;
#pragma unroll
    for (int t = 0; t < 32; ++t) {
      if (!done && v[t] == m) { v[t] = FINF; done = true; }
    }
  }
  return m;
}

// ===== featpart: feat GEMM (MFMA) + bucket-minima tau, shared A-frags =====
// grid B*64 (XCD-swizzled); 256 thr = 4 waves (rh = w>>1, jh = w&1).
__global__ __launch_bounds__(256) void featpart_kernel(
    const ushort* __restrict__ Xhi, const ushort* __restrict__ Xlo,
    const ushort* __restrict__ Vfh, const ushort* __restrict__ Vfl,
    const float* __restrict__ bias, float* __restrict__ c_out,
    float* __restrict__ u_out, const float* __restrict__ sqn,
    float* __restrict__ tau) {
  __shared__ char buf[32768];        // single-buffer async staging
  __shared__ float ldist[64 * 65];   // dist tile / minima dump

  const int tid = threadIdx.x;
  const int lane = tid & 63;
  const int w = tid >> 6;
  const int rh = w >> 1, jh = w & 1;
  const int b = blockIdx.x & 7;      // graph -> XCD
  const int i0 = (blockIdx.x >> 3) * 64;
  const size_t gb = (size_t)b * P_;

  short8 ahi[8], alo[8];
  const int arow = i0 + rh * 32 + (lane & 31);
  load_afrag_sw(Xhi, gb, arow, lane, ahi);
  load_afrag_sw(Xlo, gb, arow, lane, alo);

  // ---- feat phase: wave (rh,jh) -> rows rh*32.., col-tiles jh*4+tt ----
  const int rl = 4 * (lane >> 5);
#pragma unroll
  for (int tt = 0; tt < 4; ++tt) {
    const int t = jh * 4 + tt;       // 0..7
    floatx16 a0, a1, a2;
#pragma unroll
    for (int i = 0; i < 16; ++i) { a0[i] = 0.f; a1[i] = 0.f; a2[i] = 0.f; }
#pragma unroll
    for (int s = 0; s < 8; ++s) {
      const size_t off = (size_t)((t * 8 + s) * 64 + lane) * 8;
      short8 bh = *(const short8*)(Vfh + off);
      short8 bl = *(const short8*)(Vfl + off);
      a0 = __builtin_amdgcn_mfma_f32_32x32x16_bf16(ahi[s], bh, a0, 0, 0, 0);
      a1 = __builtin_amdgcn_mfma_f32_32x32x16_bf16(ahi[s], bl, a1, 0, 0, 0);
      a2 = __builtin_amdgcn_mfma_f32_32x32x16_bf16(alo[s], bh, a2, 0, 0, 0);
    }
    const int col = t * 32 + (lane & 31);
    if (jh == 0) {
      float bv = bias[col];
#pragma unroll
      for (int g = 0; g < 16; ++g) {
        int row = i0 + rh * 32 + rl + (g & 3) + 8 * (g >> 2);
        c_out[(gb + row) * (size_t)H_ + col] = ((a0[g] + a1[g]) + a2[g]) + bv;
      }
    } else {
#pragma unroll
      for (int g = 0; g < 16; ++g) {
        int row = i0 + rh * 32 + rl + (g & 3) + 8 * (g >> 2);
        u_out[(gb + row) * (size_t)H_ + col - 128] = (a0[g] + a1[g]) + a2[g];
      }
    }
  }

  // ---- tau phase: window [0,512); bucket minima (16-j buckets) ----
  const int rowb = rh * 32 + rl;
  const int jcol = jh * 32 + (lane & 31);
  const int srow = tid >> 2;
  const int sr = tid & 3;
  const int gi = i0 + srow;
  float bd[8];

#pragma unroll
  for (int ch = 0; ch < 8; ++ch) {
    const int tb = ch * 64;
    stage_async(Xhi, Xlo, (gb + tb) * (size_t)H_, buf, w, lane);
    float sqv = sqn[gb + tb + jcol];
    __syncthreads();                    // drain async loads
    floatx16 acc = gram32(buf, ahi, alo, jh, lane);
#pragma unroll
    for (int g = 0; g < 16; ++g) {
      ldist[(rowb + (g & 3) + 8 * (g >> 2)) * 65 + jcol] =
          fmaf(-2.f, acc[g], sqv);
    }
    __syncthreads();                    // dist ready; tile reads done
    const float* drow = ldist + srow * 65 + sr * 16;
    float m = FINF;
#pragma unroll
    for (int jj = 0; jj < 16; ++jj) {
      float s = drow[jj];
      int jg = tb + sr * 16 + jj;
      m = (jg == gi) ? m : fminf(m, s);  // exclude self from its bucket
    }
    bd[ch] = m;
  }
  __syncthreads();
#pragma unroll
  for (int k = 0; k < 8; ++k) ldist[srow * 65 + sr * 8 + k] = bd[k];
  __syncthreads();
  if (sr == 0) {
    float v[32];
#pragma unroll
    for (int t = 0; t < 32; ++t) v[t] = ldist[srow * 65 + t];
    tau[gb + gi] = kth20_of32(v);
  }
}

// ==== D=128 compact: dbuf halves, XCD-swizzled (UNCHANGED) ====
__global__ __launch_bounds__(128) void knn_compact_kernel(
    const ushort* __restrict__ Xhi, const ushort* __restrict__ Xlo,
    const float* __restrict__ sqn, const float* __restrict__ tau,
    float2* __restrict__ cand, int* __restrict__ cnt) {
  __shared__ char buf[2][16384];  // 32 KB double-buffered staging

  const int tid = threadIdx.x;
  const int lane = tid & 63;
  const int w = tid >> 6;         // wave = row-half
  const int b = blockIdx.x & 7;   // graph -> XCD
  const int rest = blockIdx.x >> 3;
  const int half = rest & 1;
  const int i0 = (rest >> 1) * 64;
  const size_t gb = (size_t)b * P_;

  short8 ahi[8], alo[8];
  const int arow = i0 + w * 32 + (lane & 31);
  load_afrag_sw(Xhi, gb, arow, lane, ahi);
  load_afrag_sw(Xlo, gb, arow, lane, alo);

  const int rowb = i0 + w * 32 + 4 * (lane >> 5);
  float taur[16];
  int cur[16];
#pragma unroll
  for (int g = 0; g < 16; ++g) {
    taur[g] = tau[gb + rowb + (g & 3) + 8 * (g >> 2)];
    cur[g] = 0;
  }
  float2* candrow = cand + (gb + rowb) * (size_t)(2 * CAPH) + half * CAPH;
  const unsigned lmask = (1u << (lane & 31)) - 1u;
  const int jbase = half * 2048;

  stage_async32(Xhi, Xlo, (gb + jbase) * (size_t)H_, buf[0], w, lane);
  float sqv_next = sqn[gb + jbase + (lane & 31)];

  for (int c = 0; c < 64; ++c) {
    const int tb = jbase + c * 32;
    __syncthreads();          // buf[c&1] staged; prior reads of other buf done
    float sqv = sqv_next;
    if (c < 63) {             // prefetch next tile; overlaps gram below
      stage_async32(Xhi, Xlo, (gb + tb + 32) * (size_t)H_, buf[(c + 1) & 1], w,
                    lane);
      sqv_next = sqn[gb + tb + 32 + (lane & 31)];
    }
    floatx16 acc = gram32t(buf[c & 1], ahi, alo, lane);
    const int jg = tb + (lane & 31);
#pragma unroll
    for (int g = 0; g < 16; ++g) {
      float d = fmaf(-2.f, acc[g], sqv);
      bool pred = (d <= taur[g]);
      unsigned long long mk = __ballot(pred);
      if (mk) {
        unsigned seg = (lane >= 32) ? (unsigned)(mk >> 32) : (unsigned)mk;
        int idx = cur[g] + __popc(seg & lmask);
        if (pred && idx < CAPH) {
          float2 e;
          e.x = d;
          e.y = __int_as_float(jg);
          candrow[(size_t)((g & 3) + 8 * (g >> 2)) * (2 * CAPH) + idx] = e;
        }
        cur[g] += __popc(seg);
      }
    }
  }
  if ((lane & 31) == 0) {
#pragma unroll
    for (int g = 0; g < 16; ++g) {
      int row = rowb + (g & 3) + 8 * (g >> 2);
      cnt[(gb + row) * 2 + half] = cur[g] < CAPH ? cur[g] : CAPH;
    }
  }
}

// ===== knn3_full: bucket-minima tau (LDS) + compact, one kernel (D=3) =====
// grid B*64*2 (XCD-swizzled); tau phase redundant across the 2 halves.
__global__ __launch_bounds__(256) void knn3_full_kernel(
    const float4* __restrict__ pt4, float2* __restrict__ cand,
    int* __restrict__ cnt) {
  __shared__ float lv[64 * 33];
  __shared__ float ltau[64];
  const int tid = threadIdx.x;
  const int b = blockIdx.x & 7;      // graph -> XCD
  const int rest = blockIdx.x >> 3;
  const int half = rest & 1;
  const int i0 = (rest >> 1) * 64;
  const size_t gb = (size_t)b * P_;

  // ---- tau phase: window [0,1024), 4 quarters x 8 buckets of 32 ----
  {
    const int row_local = tid >> 2;
    const int r = tid & 3;
    const int gi = i0 + row_local;
    float4 pi = pt4[gb + gi];
    const float4* pg = pt4 + gb + r * 256;
    float bd[8];
#pragma unroll
    for (int s = 0; s < 8; ++s) {
      float m = FINF;
#pragma unroll 4
      for (int jj = 0; jj < 32; ++jj) {
        int jl = s * 32 + jj;
        float4 v = pg[jl];
        float d = dist3(pi.x, pi.y, pi.z, v);
        int jg = r * 256 + jl;
        m = (jg == gi) ? m : fminf(m, d);  // exclude self from its bucket
      }
      bd[s] = m;
    }
#pragma unroll
    for (int k = 0; k < 8; ++k) lv[row_local * 33 + r * 8 + k] = bd[k];
    __syncthreads();
    if (r == 0) {
      float v[32];
#pragma unroll
      for (int t = 0; t < 32; ++t) v[t] = lv[row_local * 33 + t];
      ltau[row_local] = kth20_of32(v);
    }
  }
  __syncthreads();

  // ---- compact phase (identical arithmetic to R11 knn3_compact) ----
  const int lane = tid & 63;
  const int w = tid >> 6;
  const int r0 = i0 + w * 16;
  float xr0[16], xr1[16], xr2[16], taur[16];
  int cur[16];
#pragma unroll
  for (int r = 0; r < 16; ++r) {
    float4 p = pt4[gb + r0 + r];
    xr0[r] = p.x; xr1[r] = p.y; xr2[r] = p.z;
    taur[r] = ltau[w * 16 + r];
    cur[r] = 0;
  }
  const float4* pg = pt4 + gb + half * 2048;
  for (int ch = 0; ch < 32; ++ch) {
    float4 v = pg[ch * 64 + lane];
    int jg = half * 2048 + ch * 64 + lane;
#pragma unroll
    for (int r = 0; r < 16; ++r) {
      float d = dist3(xr0[r], xr1[r], xr2[r], v);
      bool pred = (d <= taur[r]);
      unsigned long long mk = __ballot(pred);
      if (mk) {
        int n = __popcll(mk);
        int pre = __popcll(mk & ((1ull << lane) - 1ull));
        int idx = cur[r] + pre;
        if (pred && idx < CAPH) {
          float2 e;
          e.x = d;
          e.y = __int_as_float(jg);
          cand[(gb + r0 + r) * (size_t)(2 * CAPH) + half * CAPH + idx] = e;
        }
        cur[r] += n;
      }
    }
  }
  if (lane == 0) {
#pragma unroll
    for (int r = 0; r < 16; ++r)
      cnt[(gb + r0 + r) * 2 + half] = cur[r] < CAPH ? cur[r] : CAPH;
  }
}

// ===== selsplit: select top-21 (drop self) + gather/max aggr + optional
//       f32 out + optional bf16 split/swizzle/sqn for the next layer =====
__global__ __launch_bounds__(256) void selsplit_kernel(
    const float2* __restrict__ cand, const int* __restrict__ cnt,
    const float* __restrict__ c, const float* __restrict__ u,
    float* __restrict__ out, ushort* __restrict__ hi,
    ushort* __restrict__ lo, float* __restrict__ sqn) {
  __shared__ int ljs[4][24];
  __shared__ float aggv[4][128];
  const int w = threadIdx.x >> 6;
  const int lane = threadIdx.x & 63;
  const int b = blockIdx.x & 7;      // graph -> XCD
  const int rowbase = b * P_ + (blockIdx.x >> 3) * 4;
  const int row = rowbase + w;
  const int c0 = cnt[row * 2], c1 = cnt[row * 2 + 1];
  const int ctot = c0 + c1;
  float d[6];
  int j[6];
#pragma unroll
  for (int s = 0; s < 6; ++s) {
    int m = s * 64 + lane;
    bool valid = m < ctot;
    int addr = (m < c0) ? m : (CAPH + m - c0);
    if (!valid) addr = 0;
    float2 e = cand[(size_t)row * (2 * CAPH) + addr];
    d[s] = valid ? e.x : FINF;
    j[s] = __float_as_int(e.y);
  }
  for (int round = 0; round < K_ + 1; ++round) {
    float bm = d[0];
    int bs = 0;
#pragma unroll
    for (int s = 1; s < 6; ++s) {
      if (d[s] < bm) { bm = d[s]; bs = s; }
    }
    int id = (lane << 3) | bs;
#pragma unroll
    for (int off = 1; off < 64; off <<= 1) {
      float od = __shfl_xor(bm, off);
      int oid = __shfl_xor(id, off);
      if (od < bm || (od == bm && oid < id)) { bm = od; id = oid; }
    }
    int owner = id >> 3, os = id & 7;
    if (lane == owner) {
      int jv = 0;
#pragma unroll
      for (int s = 0; s < 6; ++s) {
        if (s == os) { jv = j[s]; d[s] = FINF; }
      }
      ljs[w][round] = jv;
    }
  }
  // ---- aggregation: h split 2 per lane; rounds 1..20 are the neighbors
  const float2* c2p = (const float2*)(c + (size_t)row * H_);
  float2 ci = c2p[lane];
  float mx = 0.f, my = 0.f;  // relu floor
#pragma unroll 4
  for (int k = 1; k <= K_; ++k) {
    int jj = ljs[w][k];
    float2 uv = *(const float2*)(u + ((size_t)(b << 12) + jj) * H_ + lane * 2);
    mx = fmaxf(mx, ci.x + uv.x);
    my = fmaxf(my, ci.y + uv.y);
  }
  if (out != nullptr) {
    float2 o;
    o.x = mx; o.y = my;
    *(float2*)(out + (size_t)row * H_ + lane * 2) = o;
  }
  if (hi != nullptr) {
    aggv[w][lane * 2] = mx;
    aggv[w][lane * 2 + 1] = my;
    __syncthreads();
    const int tid = threadIdx.x;
    if (tid < 64) {
      const int r = tid >> 4, m = tid & 15;
      const int rrow = rowbase + r;
      float vv[8];
      float ss = 0.f;
      ushort hh[8], ll[8];
#pragma unroll
      for (int e = 0; e < 8; ++e) {
        vv[e] = aggv[r][m * 8 + e];
        ss = fmaf(vv[e], vv[e], ss);
        cvt_split(vv[e], hh[e], ll[e]);
      }
      size_t dst = ((size_t)rrow << 7) + ((size_t)(m ^ (rrow & 15)) << 3);
      *(short8*)(hi + dst) = *(short8*)hh;
      *(short8*)(lo + dst) = *(short8*)ll;
#pragma unroll
      for (int off = 1; off < 16; off <<= 1) ss += __shfl_xor(ss, off);
      if (m == 0) sqn[rrow] = ss;
    }
  }
}

// ---------------- head: mean pool (partials) + MLP ----------------
__global__ __launch_bounds__(128) void pool_kernel(const float* __restrict__ hf,
                                                   float* __restrict__ psum) {
  constexpr int CHUNK = 64;
  int blk = blockIdx.x;       // B_*64
  int b = blk >> 6;
  int chunk = blk & 63;
  int h = threadIdx.x;
  int base = (b << 12) + chunk * CHUNK;
  float acc = 0.f;
#pragma unroll 4
  for (int p = 0; p < CHUNK; ++p) acc += hf[(size_t)(base + p) * H_ + h];
  psum[blk * H_ + h] = acc;
}

__global__ __launch_bounds__(128) void head_kernel(
    const float* __restrict__ psum, const float* __restrict__ W4,
    const float* __restrict__ b4, const float* __restrict__ W5,
    const float* __restrict__ b5, float* __restrict__ out) {
  int b = blockIdx.x, h = threadIdx.x;
  __shared__ float g[H_];
  __shared__ float t[H_];
  float s = 0.f;
#pragma unroll 4
  for (int ch = 0; ch < 64; ++ch) s += psum[(b * 64 + ch) * H_ + h];
  g[h] = s * (1.0f / P_);
  __syncthreads();
  float acc = b4[h];
#pragma unroll 4
  for (int d = 0; d < H_; ++d) acc = fmaf(g[d], W4[d * H_ + h], acc);
  t[h] = fmaxf(acc, 0.f);
  __syncthreads();
  if (h < 3) {
    float o = b5[h];
#pragma unroll 4
    for (int d = 0; d < H_; ++d) o = fmaf(t[d], W5[d * 3 + h], o);
    out[b * 3 + h] = o;
  }
}

extern "C" void kernel_launch(void* const* d_in, const int* in_sizes, int n_in,
                              void* d_out, int out_size, void* d_ws,
                              size_t ws_size, hipStream_t stream) {
  const float* x  = (const float*)d_in[0];
  const float* W1 = (const float*)d_in[1];
  const float* b1 = (const float*)d_in[2];
  const float* W2 = (const float*)d_in[3];
  const float* b2 = (const float*)d_in[4];
  const float* W3 = (const float*)d_in[5];
  const float* b3 = (const float*)d_in[6];
  const float* W4 = (const float*)d_in[7];
  const float* b4 = (const float*)d_in[8];
  const float* W5 = (const float*)d_in[9];
  const float* b5 = (const float*)d_in[10];
  float* out = (float*)d_out;

  char* ws = (char*)d_ws;
  const size_t NF = (size_t)B_ * P_ * H_;   // 4,194,304
  const size_t NP_ = (size_t)B_ * P_;       // 32768
  float*  bufA = (float*)ws;  ws += NF * 4;
  float*  bufB = (float*)ws;  ws += NF * 4;
  float*  bufU = (float*)ws;  ws += NF * 4;
  ushort* xhi  = (ushort*)ws; ws += NF * 2;
  ushort* xlo  = (ushort*)ws; ws += NF * 2;
  float*  sqn  = (float*)ws;  ws += NP_ * 4;
  float*  psum = (float*)ws;  ws += (size_t)B_ * 64 * H_ * 4;
  float*  tau  = (float*)ws;  ws += NP_ * 4;
  int*    cnt  = (int*)ws;    ws += NP_ * 2 * 4;
  float4* pt4  = (float4*)ws; ws += NP_ * 16;
  ushort* vfh2 = (ushort*)ws; ws += 32768 * 2;
  ushort* vfl2 = (ushort*)ws; ws += 32768 * 2;
  ushort* vfh3 = (ushort*)ws; ws += 32768 * 2;
  ushort* vfl3 = (ushort*)ws; ws += 32768 * 2;
  float2* cand = (float2*)ws; ws += NP_ * (size_t)(2 * CAPH) * 8;

  const int NP = B_ * P_;
  dim3 blk256(256), blk128(128);

  // ---- weight prep for layers 2+3 (no deps on pipeline)
  wprep2_kernel<<<32, blk256, 0, stream>>>(W2, W3, vfh2, vfl2, vfh3, vfl3);

  // ---- layer 1 (D=3)
  feat3p_kernel<<<NP / 8, blk256, 0, stream>>>(x, W1, b1, bufA, bufU, pt4);
  knn3_full_kernel<<<B_ * 64 * 2, blk256, 0, stream>>>(pt4, cand, cnt);
  selsplit_kernel<<<NP / 4, blk256, 0, stream>>>(cand, cnt, bufA, bufU,
                                                 nullptr, xhi, xlo, sqn);

  // ---- layer 2 (D=128)
  featpart_kernel<<<B_ * 64, blk256, 0, stream>>>(xhi, xlo, vfh2, vfl2, b2,
                                                  bufB, bufU, sqn, tau);
  knn_compact_kernel<<<B_ * 64 * 2, blk128, 0, stream>>>(xhi, xlo, sqn, tau,
                                                         cand, cnt);
  selsplit_kernel<<<NP / 4, blk256, 0, stream>>>(cand, cnt, bufB, bufU,
                                                 nullptr, xhi, xlo, sqn);

  // ---- layer 3 (D=128)
  featpart_kernel<<<B_ * 64, blk256, 0, stream>>>(xhi, xlo, vfh3, vfl3, b3,
                                                  bufB, bufU, sqn, tau);
  knn_compact_kernel<<<B_ * 64 * 2, blk128, 0, stream>>>(xhi, xlo, sqn, tau,
                                                         cand, cnt);
  selsplit_kernel<<<NP / 4, blk256, 0, stream>>>(cand, cnt, bufB, bufU,
                                                 bufA, nullptr, nullptr,
                                                 nullptr);

  // ---- head
  pool_kernel<<<B_ * 64, blk128, 0, stream>>>(bufA, psum);
  head_kernel<<<B_, blk128, 0, stream>>>(psum, W4, b4, W5, b5, out);
}

// Round 15
// 919.729 us; speedup vs baseline: 1.2815x; 1.1617x over previous
//
#include <hip/hip_runtime.h>
#include <hip/hip_bf16.h>

// DGCNN: B=8, P=4096, K=20, H=128.
// EdgeConv: relu([xi, xj-xi]@W + b) == relu(c_i + u_j).
// kNN: gram via 32x32x16 MFMA split-bf16 (3 indep chains hh/hl/lh);
// threshold compaction -> ballot-compact from MFMA C-layout registers ->
// select 21 rounds dropping self, fused with gather/max aggregation.
// R15: knn3_full single-block-per-rowgroup (tau once, full-row cand cap 384,
//      prefetched j-loads); kth20 via 4-lane cooperative remove-12-maxima
//      (exact, ~4x fewer inst, no serial chain) in knn3 + featpart; featpart
//      tau straight from registers (LDS dump deleted).

static constexpr int B_ = 8, P_ = 4096, K_ = 20, H_ = 128;
static constexpr float FINF = 3.0e38f;
static constexpr int CAPH = 192;  // per-half cap (D=128); D=3 full-row = 384

typedef __attribute__((ext_vector_type(8))) short short8;
typedef __attribute__((ext_vector_type(16))) float floatx16;

__device__ __forceinline__ float dist3(float x0, float x1, float x2,
                                       const float4& v) {
  // MUST be bit-identical between tau and compact phases.
  return fmaf(-2.f, fmaf(x0, v.x, fmaf(x1, v.y, x2 * v.z)), v.w);
}

__device__ __forceinline__ void cvt_split(float v, ushort& h, ushort& l) {
  __hip_bfloat16 hb = __float2bfloat16(v);
  float hf = __bfloat162float(hb);
  __hip_bfloat16 lb = __float2bfloat16(v - hf);
  h = *(ushort*)&hb;
  l = *(ushort*)&lb;
}

// exact 20th-smallest of 32 values spread over 4 consecutive lanes (8 each):
// remove the 12 largest (id-tiebroken), then max of the remaining 20.
__device__ __forceinline__ float kth20_par4(float* v, int lane) {
  const int sub = lane & 3;
  for (int r = 0; r < 12; ++r) {
    float lm = v[0];
    int la = 0;
#pragma unroll
    for (int t = 1; t < 8; ++t) {
      if (v[t] > lm) { lm = v[t]; la = t; }
    }
    int gid = sub * 8 + la;
#pragma unroll
    for (int off = 1; off < 4; off <<= 1) {
      float om = __shfl_xor(lm, off);
      int oid = __shfl_xor(gid, off);
      if (om > lm || (om == lm && oid > gid)) { lm = om; gid = oid; }
    }
    if ((gid >> 3) == sub) v[gid & 7] = -FINF;
  }
  float lm = v[0];
#pragma unroll
  for (int t = 1; t < 8; ++t) lm = fmaxf(lm, v[t]);
#pragma unroll
  for (int off = 1; off < 4; off <<= 1) lm = fmaxf(lm, __shfl_xor(lm, off));
  return lm;
}

// ---------------- layer-1 c/u GEMM (D=3) + pt4 pack ----------------
__global__ __launch_bounds__(256) void feat3p_kernel(
    const float* __restrict__ X, const float* __restrict__ W,
    const float* __restrict__ bias, float* __restrict__ c_out,
    float* __restrict__ u_out, float4* __restrict__ pt4) {
  const int h = threadIdx.x & (H_ - 1);
  const int pg = threadIdx.x >> 7;
  const int bb = blockIdx.x & 7;          // graph -> XCD
  const int pb = blockIdx.x >> 3;
  const int pbase = bb * P_ + pb * 8;
  const int p0 = pbase + pg * 4;
  if (threadIdx.x < 8) {                  // fused pack4 for the 8 points
    const float* row = X + (size_t)(pbase + threadIdx.x) * 3;
    float4 v;
    v.x = row[0]; v.y = row[1]; v.z = row[2];
    v.w = fmaf(v.x, v.x, fmaf(v.y, v.y, v.z * v.z));
    pt4[pbase + threadIdx.x] = v;
  }
  float a0 = 0, a1 = 0, a2 = 0, a3 = 0, u0 = 0, u1 = 0, u2 = 0, u3 = 0;
  const float* xp = X + (size_t)p0 * 3;
#pragma unroll
  for (int d = 0; d < 3; ++d) {
    float wt = W[d * H_ + h];
    float wb = W[(3 + d) * H_ + h];
    float x0 = xp[d], x1 = xp[3 + d], x2 = xp[6 + d], x3 = xp[9 + d];
    a0 = fmaf(x0, wt, a0); u0 = fmaf(x0, wb, u0);
    a1 = fmaf(x1, wt, a1); u1 = fmaf(x1, wb, u1);
    a2 = fmaf(x2, wt, a2); u2 = fmaf(x2, wb, u2);
    a3 = fmaf(x3, wt, a3); u3 = fmaf(x3, wb, u3);
  }
  float bv = bias[h];
  c_out[(size_t)(p0 + 0) * H_ + h] = a0 - u0 + bv;
  c_out[(size_t)(p0 + 1) * H_ + h] = a1 - u1 + bv;
  c_out[(size_t)(p0 + 2) * H_ + h] = a2 - u2 + bv;
  c_out[(size_t)(p0 + 3) * H_ + h] = a3 - u3 + bv;
  u_out[(size_t)(p0 + 0) * H_ + h] = u0;
  u_out[(size_t)(p0 + 1) * H_ + h] = u1;
  u_out[(size_t)(p0 + 2) * H_ + h] = u2;
  u_out[(size_t)(p0 + 3) * H_ + h] = u3;
}

// ===== W prep (both layers): V = [Wt-Wb ; Wb] -> bf16 hi/lo B-frag order ===
__global__ __launch_bounds__(256) void wprep2_kernel(
    const float* __restrict__ W2, const float* __restrict__ W3,
    ushort* __restrict__ Vfh2, ushort* __restrict__ Vfl2,
    ushort* __restrict__ Vfh3, ushort* __restrict__ Vfl3) {
  const int which = blockIdx.x >> 4;  // 0 -> W2, 1 -> W3
  const float* W = which ? W3 : W2;
  ushort* Vfh = which ? Vfh3 : Vfh2;
  ushort* Vfl = which ? Vfl3 : Vfl2;
  int tid = (blockIdx.x & 15) * 256 + threadIdx.x;  // 4096 per weight
  int t = tid >> 9;
  int s = (tid >> 6) & 7;
  int lane = tid & 63;
  int col = t * 32 + (lane & 31);
  int kb = s * 16 + ((lane >> 5) << 3);
  ushort h[8], l[8];
#pragma unroll
  for (int e = 0; e < 8; ++e) {
    int k = kb + e;
    float v;
    if (col < 128) v = W[k * H_ + col] - W[(128 + k) * H_ + col];
    else v = W[(128 + k) * H_ + col - 128];
    cvt_split(v, h[e], l[e]);
  }
  size_t off = (size_t)((t * 8 + s) * 64 + lane) * 8;
  *(short8*)(Vfh + off) = *(short8*)h;
  *(short8*)(Vfl + off) = *(short8*)l;
}

// =============== shared gram machinery (D=128) ===============
__device__ __forceinline__ void stage_async(const ushort* __restrict__ Xhi,
                                            const ushort* __restrict__ Xlo,
                                            size_t tile, char* buf, int w,
                                            int lane) {
  const char* gh = (const char*)(Xhi + tile);
  const char* gl = (const char*)(Xlo + tile);
  const int lo16 = lane * 16;
#pragma unroll
  for (int it = 0; it < 4; ++it) {
    const int off = (w * 4 + it) * 1024;
    __builtin_amdgcn_global_load_lds(
        (const __attribute__((address_space(1))) void*)(gh + off + lo16),
        (__attribute__((address_space(3))) void*)(buf + off), 16, 0, 0);
    __builtin_amdgcn_global_load_lds(
        (const __attribute__((address_space(1))) void*)(gl + off + lo16),
        (__attribute__((address_space(3))) void*)(buf + 16384 + off), 16, 0, 0);
  }
}

__device__ __forceinline__ void stage_async32(const ushort* __restrict__ Xhi,
                                              const ushort* __restrict__ Xlo,
                                              size_t tile, char* buf, int w,
                                              int lane) {
  const char* gh = (const char*)(Xhi + tile);
  const char* gl = (const char*)(Xlo + tile);
  const int lo16 = lane * 16;
#pragma unroll
  for (int it = 0; it < 4; ++it) {
    const int off = (w * 4 + it) * 1024;
    __builtin_amdgcn_global_load_lds(
        (const __attribute__((address_space(1))) void*)(gh + off + lo16),
        (__attribute__((address_space(3))) void*)(buf + off), 16, 0, 0);
    __builtin_amdgcn_global_load_lds(
        (const __attribute__((address_space(1))) void*)(gl + off + lo16),
        (__attribute__((address_space(3))) void*)(buf + 8192 + off), 16, 0, 0);
  }
}

__device__ __forceinline__ void load_afrag_sw(const ushort* __restrict__ X,
                                              size_t gb, int row, int lane,
                                              short8* a) {
  const ushort* base = X + (gb + row) * (size_t)H_;
  const int x = row & 15;
  const int kh = lane >> 5;
#pragma unroll
  for (int s = 0; s < 8; ++s) {
    a[s] = *(const short8*)(base + (((s * 2 + kh) ^ x) << 3));
  }
}

// 32x32 gram tile, 64-j tile layout (lo at +16384). Combine (a0+a1)+a2
// MUST match gram32t exactly.
__device__ __forceinline__ floatx16 gram32(const char* lds, const short8* ahi,
                                           const short8* alo, int jh,
                                           int lane) {
  floatx16 a0, a1, a2;
#pragma unroll
  for (int i = 0; i < 16; ++i) { a0[i] = 0.f; a1[i] = 0.f; a2[i] = 0.f; }
  const int base = (jh * 32 + (lane & 31)) * 256;
  const int kh = lane >> 5;
  const int x = lane & 15;
#pragma unroll
  for (int s = 0; s < 8; ++s) {
    const int off = base + (((s * 2 + kh) ^ x) << 4);
    short8 bh = *(const short8*)(lds + off);
    short8 bl = *(const short8*)(lds + 16384 + off);
    a0 = __builtin_amdgcn_mfma_f32_32x32x16_bf16(ahi[s], bh, a0, 0, 0, 0);
    a1 = __builtin_amdgcn_mfma_f32_32x32x16_bf16(ahi[s], bl, a1, 0, 0, 0);
    a2 = __builtin_amdgcn_mfma_f32_32x32x16_bf16(alo[s], bh, a2, 0, 0, 0);
  }
  floatx16 acc;
#pragma unroll
  for (int i = 0; i < 16; ++i) acc[i] = (a0[i] + a1[i]) + a2[i];
  return acc;
}

// 32x32 gram tile, 32-j tile layout (lo at +8192). Same value-order.
__device__ __forceinline__ floatx16 gram32t(const char* lds, const short8* ahi,
                                            const short8* alo, int lane) {
  floatx16 a0, a1, a2;
#pragma unroll
  for (int i = 0; i < 16; ++i) { a0[i] = 0.f; a1[i] = 0.f; a2[i] = 0.f; }
  const int base = (lane & 31) * 256;
  const int kh = lane >> 5;
  const int x = lane & 15;
#pragma unroll
  for (int s = 0; s < 8; ++s) {
    const int off = base + (((s * 2 + kh) ^ x) << 4);
    short8 bh = *(const short8*)(lds + off);
    short8 bl = *(const short8*)(lds + 8192 + off);
    a0 = __builtin_amdgcn_mfma_f32_32x32x16_bf16(ahi[s], bh, a0, 0, 0, 0);
    a1 = __builtin_amdgcn_mfma_f32_32x32x16_bf16(ahi[s], bl, a1, 0, 0, 0);
    a2 = __builtin_amdgcn_mfma_f32_32x32x16_bf16(alo[s], bh, a2, 0, 0, 0);
  }
  floatx16 acc;
#pragma unroll
  for (int i = 0; i < 16; ++i) acc[i] = (a0[i] + a1[i]) + a2[i];
  return acc;
}

// ===== featpart: feat GEMM (MFMA) + bucket-minima tau, shared A-frags =====
// grid B*64 (XCD-swizzled); 256 thr = 4 waves (rh = w>>1, jh = w&1).
__global__ __launch_bounds__(256) void featpart_kernel(
    const ushort* __restrict__ Xhi, const ushort* __restrict__ Xlo,
    const ushort* __restrict__ Vfh, const ushort* __restrict__ Vfl,
    const float* __restrict__ bias, float* __restrict__ c_out,
    float* __restrict__ u_out, const float* __restrict__ sqn,
    float* __restrict__ tau) {
  __shared__ char buf[32768];        // single-buffer async staging
  __shared__ float ldist[64 * 65];   // dist tile

  const int tid = threadIdx.x;
  const int lane = tid & 63;
  const int w = tid >> 6;
  const int rh = w >> 1, jh = w & 1;
  const int b = blockIdx.x & 7;      // graph -> XCD
  const int i0 = (blockIdx.x >> 3) * 64;
  const size_t gb = (size_t)b * P_;

  short8 ahi[8], alo[8];
  const int arow = i0 + rh * 32 + (lane & 31);
  load_afrag_sw(Xhi, gb, arow, lane, ahi);
  load_afrag_sw(Xlo, gb, arow, lane, alo);

  // ---- feat phase: wave (rh,jh) -> rows rh*32.., col-tiles jh*4+tt ----
  const int rl = 4 * (lane >> 5);
#pragma unroll
  for (int tt = 0; tt < 4; ++tt) {
    const int t = jh * 4 + tt;       // 0..7
    floatx16 a0, a1, a2;
#pragma unroll
    for (int i = 0; i < 16; ++i) { a0[i] = 0.f; a1[i] = 0.f; a2[i] = 0.f; }
#pragma unroll
    for (int s = 0; s < 8; ++s) {
      const size_t off = (size_t)((t * 8 + s) * 64 + lane) * 8;
      short8 bh = *(const short8*)(Vfh + off);
      short8 bl = *(const short8*)(Vfl + off);
      a0 = __builtin_amdgcn_mfma_f32_32x32x16_bf16(ahi[s], bh, a0, 0, 0, 0);
      a1 = __builtin_amdgcn_mfma_f32_32x32x16_bf16(ahi[s], bl, a1, 0, 0, 0);
      a2 = __builtin_amdgcn_mfma_f32_32x32x16_bf16(alo[s], bh, a2, 0, 0, 0);
    }
    const int col = t * 32 + (lane & 31);
    if (jh == 0) {
      float bv = bias[col];
#pragma unroll
      for (int g = 0; g < 16; ++g) {
        int row = i0 + rh * 32 + rl + (g & 3) + 8 * (g >> 2);
        c_out[(gb + row) * (size_t)H_ + col] = ((a0[g] + a1[g]) + a2[g]) + bv;
      }
    } else {
#pragma unroll
      for (int g = 0; g < 16; ++g) {
        int row = i0 + rh * 32 + rl + (g & 3) + 8 * (g >> 2);
        u_out[(gb + row) * (size_t)H_ + col - 128] = (a0[g] + a1[g]) + a2[g];
      }
    }
  }

  // ---- tau phase: window [0,512); bucket minima (16-j buckets) ----
  const int rowb = rh * 32 + rl;
  const int jcol = jh * 32 + (lane & 31);
  const int srow = tid >> 2;
  const int sr = tid & 3;
  const int gi = i0 + srow;
  float bd[8];

#pragma unroll
  for (int ch = 0; ch < 8; ++ch) {
    const int tb = ch * 64;
    stage_async(Xhi, Xlo, (gb + tb) * (size_t)H_, buf, w, lane);
    float sqv = sqn[gb + tb + jcol];
    __syncthreads();                    // drain async loads
    floatx16 acc = gram32(buf, ahi, alo, jh, lane);
#pragma unroll
    for (int g = 0; g < 16; ++g) {
      ldist[(rowb + (g & 3) + 8 * (g >> 2)) * 65 + jcol] =
          fmaf(-2.f, acc[g], sqv);
    }
    __syncthreads();                    // dist ready; tile reads done
    const float* drow = ldist + srow * 65 + sr * 16;
    float m = FINF;
#pragma unroll
    for (int jj = 0; jj < 16; ++jj) {
      float s = drow[jj];
      int jg = tb + sr * 16 + jj;
      m = (jg == gi) ? m : fminf(m, s);  // exclude self from its bucket
    }
    bd[ch] = m;
  }
  // exact 20th of the 32 bucket minima, straight from registers
  float t20 = kth20_par4(bd, lane);
  if (sr == 0) tau[gb + gi] = t20;
}

// ==== D=128 compact: dbuf halves, XCD-swizzled (UNCHANGED) ====
__global__ __launch_bounds__(128) void knn_compact_kernel(
    const ushort* __restrict__ Xhi, const ushort* __restrict__ Xlo,
    const float* __restrict__ sqn, const float* __restrict__ tau,
    float2* __restrict__ cand, int* __restrict__ cnt) {
  __shared__ char buf[2][16384];  // 32 KB double-buffered staging

  const int tid = threadIdx.x;
  const int lane = tid & 63;
  const int w = tid >> 6;         // wave = row-half
  const int b = blockIdx.x & 7;   // graph -> XCD
  const int rest = blockIdx.x >> 3;
  const int half = rest & 1;
  const int i0 = (rest >> 1) * 64;
  const size_t gb = (size_t)b * P_;

  short8 ahi[8], alo[8];
  const int arow = i0 + w * 32 + (lane & 31);
  load_afrag_sw(Xhi, gb, arow, lane, ahi);
  load_afrag_sw(Xlo, gb, arow, lane, alo);

  const int rowb = i0 + w * 32 + 4 * (lane >> 5);
  float taur[16];
  int cur[16];
#pragma unroll
  for (int g = 0; g < 16; ++g) {
    taur[g] = tau[gb + rowb + (g & 3) + 8 * (g >> 2)];
    cur[g] = 0;
  }
  float2* candrow = cand + (gb + rowb) * (size_t)(2 * CAPH) + half * CAPH;
  const unsigned lmask = (1u << (lane & 31)) - 1u;
  const int jbase = half * 2048;

  stage_async32(Xhi, Xlo, (gb + jbase) * (size_t)H_, buf[0], w, lane);
  float sqv_next = sqn[gb + jbase + (lane & 31)];

  for (int c = 0; c < 64; ++c) {
    const int tb = jbase + c * 32;
    __syncthreads();          // buf[c&1] staged; prior reads of other buf done
    float sqv = sqv_next;
    if (c < 63) {             // prefetch next tile; overlaps gram below
      stage_async32(Xhi, Xlo, (gb + tb + 32) * (size_t)H_, buf[(c + 1) & 1], w,
                    lane);
      sqv_next = sqn[gb + tb + 32 + (lane & 31)];
    }
    floatx16 acc = gram32t(buf[c & 1], ahi, alo, lane);
    const int jg = tb + (lane & 31);
#pragma unroll
    for (int g = 0; g < 16; ++g) {
      float d = fmaf(-2.f, acc[g], sqv);
      bool pred = (d <= taur[g]);
      unsigned long long mk = __ballot(pred);
      if (mk) {
        unsigned seg = (lane >= 32) ? (unsigned)(mk >> 32) : (unsigned)mk;
        int idx = cur[g] + __popc(seg & lmask);
        if (pred && idx < CAPH) {
          float2 e;
          e.x = d;
          e.y = __int_as_float(jg);
          candrow[(size_t)((g & 3) + 8 * (g >> 2)) * (2 * CAPH) + idx] = e;
        }
        cur[g] += __popc(seg);
      }
    }
  }
  if ((lane & 31) == 0) {
#pragma unroll
    for (int g = 0; g < 16; ++g) {
      int row = rowb + (g & 3) + 8 * (g >> 2);
      cnt[(gb + row) * 2 + half] = cur[g] < CAPH ? cur[g] : CAPH;
    }
  }
}

// ===== knn3_full: one block per rowgroup; tau once + full-4096 compact =====
// grid B*64 (XCD-swizzled); cand written contiguously, cap 384 (=2*CAPH);
// cnt[row*2]=count, cnt[row*2+1]=0 so select works unchanged.
__global__ __launch_bounds__(256) void knn3_full_kernel(
    const float4* __restrict__ pt4, float2* __restrict__ cand,
    int* __restrict__ cnt) {
  __shared__ float ltau[64];
  const int tid = threadIdx.x;
  const int b = blockIdx.x & 7;      // graph -> XCD
  const int i0 = (blockIdx.x >> 3) * 64;
  const size_t gb = (size_t)b * P_;

  // ---- tau phase: window [0,1024), 4 quarters x 8 buckets of 32 ----
  {
    const int row_local = tid >> 2;
    const int r = tid & 3;
    const int gi = i0 + row_local;
    float4 pi = pt4[gb + gi];
    const float4* pg = pt4 + gb + r * 256;
    float bd[8];
#pragma unroll
    for (int s = 0; s < 8; ++s) {
      float m = FINF;
#pragma unroll 4
      for (int jj = 0; jj < 32; ++jj) {
        int jl = s * 32 + jj;
        float4 v = pg[jl];
        float d = dist3(pi.x, pi.y, pi.z, v);
        int jg = r * 256 + jl;
        m = (jg == gi) ? m : fminf(m, d);  // exclude self from its bucket
      }
      bd[s] = m;
    }
    float t20 = kth20_par4(bd, tid & 63);
    if (r == 0) ltau[row_local] = t20;
  }
  __syncthreads();

  // ---- compact phase: full 4096 j, contiguous cand from 0, cap 384 ----
  const int lane = tid & 63;
  const int w = tid >> 6;
  const int r0 = i0 + w * 16;
  float xr0[16], xr1[16], xr2[16], taur[16];
  int cur[16];
#pragma unroll
  for (int r = 0; r < 16; ++r) {
    float4 p = pt4[gb + r0 + r];
    xr0[r] = p.x; xr1[r] = p.y; xr2[r] = p.z;
    taur[r] = ltau[w * 16 + r];
    cur[r] = 0;
  }
  const float4* pg = pt4 + gb;
  float4 v = pg[lane];
  for (int ch = 0; ch < 64; ++ch) {
    float4 vn;
    if (ch < 63) vn = pg[(ch + 1) * 64 + lane];  // prefetch next chunk
    const int jg = ch * 64 + lane;
#pragma unroll
    for (int r = 0; r < 16; ++r) {
      float d = dist3(xr0[r], xr1[r], xr2[r], v);
      bool pred = (d <= taur[r]);
      unsigned long long mk = __ballot(pred);
      if (mk) {
        int n = __popcll(mk);
        int pre = __popcll(mk & ((1ull << lane) - 1ull));
        int idx = cur[r] + pre;
        if (pred && idx < 2 * CAPH) {
          float2 e;
          e.x = d;
          e.y = __int_as_float(jg);
          cand[(gb + r0 + r) * (size_t)(2 * CAPH) + idx] = e;
        }
        cur[r] += n;
      }
    }
    v = vn;
  }
  if (lane == 0) {
#pragma unroll
    for (int r = 0; r < 16; ++r) {
      cnt[(gb + r0 + r) * 2] = cur[r] < 2 * CAPH ? cur[r] : 2 * CAPH;
      cnt[(gb + r0 + r) * 2 + 1] = 0;
    }
  }
}

// ===== selsplit: select top-21 (drop self) + gather/max aggr + optional
//       f32 out + optional bf16 split/swizzle/sqn for the next layer =====
__global__ __launch_bounds__(256) void selsplit_kernel(
    const float2* __restrict__ cand, const int* __restrict__ cnt,
    const float* __restrict__ c, const float* __restrict__ u,
    float* __restrict__ out, ushort* __restrict__ hi,
    ushort* __restrict__ lo, float* __restrict__ sqn) {
  __shared__ int ljs[4][24];
  __shared__ float aggv[4][128];
  const int w = threadIdx.x >> 6;
  const int lane = threadIdx.x & 63;
  const int b = blockIdx.x & 7;      // graph -> XCD
  const int rowbase = b * P_ + (blockIdx.x >> 3) * 4;
  const int row = rowbase + w;
  const int c0 = cnt[row * 2], c1 = cnt[row * 2 + 1];
  const int ctot = c0 + c1;
  float d[6];
  int j[6];
#pragma unroll
  for (int s = 0; s < 6; ++s) {
    int m = s * 64 + lane;
    bool valid = m < ctot;
    int addr = (m < c0) ? m : (CAPH + m - c0);
    if (!valid) addr = 0;
    float2 e = cand[(size_t)row * (2 * CAPH) + addr];
    d[s] = valid ? e.x : FINF;
    j[s] = __float_as_int(e.y);
  }
  for (int round = 0; round < K_ + 1; ++round) {
    float bm = d[0];
    int bs = 0;
#pragma unroll
    for (int s = 1; s < 6; ++s) {
      if (d[s] < bm) { bm = d[s]; bs = s; }
    }
    int id = (lane << 3) | bs;
#pragma unroll
    for (int off = 1; off < 64; off <<= 1) {
      float od = __shfl_xor(bm, off);
      int oid = __shfl_xor(id, off);
      if (od < bm || (od == bm && oid < id)) { bm = od; id = oid; }
    }
    int owner = id >> 3, os = id & 7;
    if (lane == owner) {
      int jv = 0;
#pragma unroll
      for (int s = 0; s < 6; ++s) {
        if (s == os) { jv = j[s]; d[s] = FINF; }
      }
      ljs[w][round] = jv;
    }
  }
  // ---- aggregation: h split 2 per lane; rounds 1..20 are the neighbors
  const float2* c2p = (const float2*)(c + (size_t)row * H_);
  float2 ci = c2p[lane];
  float mx = 0.f, my = 0.f;  // relu floor
#pragma unroll 4
  for (int k = 1; k <= K_; ++k) {
    int jj = ljs[w][k];
    float2 uv = *(const float2*)(u + ((size_t)(b << 12) + jj) * H_ + lane * 2);
    mx = fmaxf(mx, ci.x + uv.x);
    my = fmaxf(my, ci.y + uv.y);
  }
  if (out != nullptr) {
    float2 o;
    o.x = mx; o.y = my;
    *(float2*)(out + (size_t)row * H_ + lane * 2) = o;
  }
  if (hi != nullptr) {
    aggv[w][lane * 2] = mx;
    aggv[w][lane * 2 + 1] = my;
    __syncthreads();
    const int tid = threadIdx.x;
    if (tid < 64) {
      const int r = tid >> 4, m = tid & 15;
      const int rrow = rowbase + r;
      float vv[8];
      float ss = 0.f;
      ushort hh[8], ll[8];
#pragma unroll
      for (int e = 0; e < 8; ++e) {
        vv[e] = aggv[r][m * 8 + e];
        ss = fmaf(vv[e], vv[e], ss);
        cvt_split(vv[e], hh[e], ll[e]);
      }
      size_t dst = ((size_t)rrow << 7) + ((size_t)(m ^ (rrow & 15)) << 3);
      *(short8*)(hi + dst) = *(short8*)hh;
      *(short8*)(lo + dst) = *(short8*)ll;
#pragma unroll
      for (int off = 1; off < 16; off <<= 1) ss += __shfl_xor(ss, off);
      if (m == 0) sqn[rrow] = ss;
    }
  }
}

// ---------------- head: mean pool (partials) + MLP ----------------
__global__ __launch_bounds__(128) void pool_kernel(const float* __restrict__ hf,
                                                   float* __restrict__ psum) {
  constexpr int CHUNK = 64;
  int blk = blockIdx.x;       // B_*64
  int b = blk >> 6;
  int chunk = blk & 63;
  int h = threadIdx.x;
  int base = (b << 12) + chunk * CHUNK;
  float acc = 0.f;
#pragma unroll 4
  for (int p = 0; p < CHUNK; ++p) acc += hf[(size_t)(base + p) * H_ + h];
  psum[blk * H_ + h] = acc;
}

__global__ __launch_bounds__(128) void head_kernel(
    const float* __restrict__ psum, const float* __restrict__ W4,
    const float* __restrict__ b4, const float* __restrict__ W5,
    const float* __restrict__ b5, float* __restrict__ out) {
  int b = blockIdx.x, h = threadIdx.x;
  __shared__ float g[H_];
  __shared__ float t[H_];
  float s = 0.f;
#pragma unroll 4
  for (int ch = 0; ch < 64; ++ch) s += psum[(b * 64 + ch) * H_ + h];
  g[h] = s * (1.0f / P_);
  __syncthreads();
  float acc = b4[h];
#pragma unroll 4
  for (int d = 0; d < H_; ++d) acc = fmaf(g[d], W4[d * H_ + h], acc);
  t[h] = fmaxf(acc, 0.f);
  __syncthreads();
  if (h < 3) {
    float o = b5[h];
#pragma unroll 4
    for (int d = 0; d < H_; ++d) o = fmaf(t[d], W5[d * 3 + h], o);
    out[b * 3 + h] = o;
  }
}

extern "C" void kernel_launch(void* const* d_in, const int* in_sizes, int n_in,
                              void* d_out, int out_size, void* d_ws,
                              size_t ws_size, hipStream_t stream) {
  const float* x  = (const float*)d_in[0];
  const float* W1 = (const float*)d_in[1];
  const float* b1 = (const float*)d_in[2];
  const float* W2 = (const float*)d_in[3];
  const float* b2 = (const float*)d_in[4];
  const float* W3 = (const float*)d_in[5];
  const float* b3 = (const float*)d_in[6];
  const float* W4 = (const float*)d_in[7];
  const float* b4 = (const float*)d_in[8];
  const float* W5 = (const float*)d_in[9];
  const float* b5 = (const float*)d_in[10];
  float* out = (float*)d_out;

  char* ws = (char*)d_ws;
  const size_t NF = (size_t)B_ * P_ * H_;   // 4,194,304
  const size_t NP_ = (size_t)B_ * P_;       // 32768
  float*  bufA = (float*)ws;  ws += NF * 4;
  float*  bufB = (float*)ws;  ws += NF * 4;
  float*  bufU = (float*)ws;  ws += NF * 4;
  ushort* xhi  = (ushort*)ws; ws += NF * 2;
  ushort* xlo  = (ushort*)ws; ws += NF * 2;
  float*  sqn  = (float*)ws;  ws += NP_ * 4;
  float*  psum = (float*)ws;  ws += (size_t)B_ * 64 * H_ * 4;
  float*  tau  = (float*)ws;  ws += NP_ * 4;
  int*    cnt  = (int*)ws;    ws += NP_ * 2 * 4;
  float4* pt4  = (float4*)ws; ws += NP_ * 16;
  ushort* vfh2 = (ushort*)ws; ws += 32768 * 2;
  ushort* vfl2 = (ushort*)ws; ws += 32768 * 2;
  ushort* vfh3 = (ushort*)ws; ws += 32768 * 2;
  ushort* vfl3 = (ushort*)ws; ws += 32768 * 2;
  float2* cand = (float2*)ws; ws += NP_ * (size_t)(2 * CAPH) * 8;

  const int NP = B_ * P_;
  dim3 blk256(256), blk128(128);

  // ---- weight prep for layers 2+3 (no deps on pipeline)
  wprep2_kernel<<<32, blk256, 0, stream>>>(W2, W3, vfh2, vfl2, vfh3, vfl3);

  // ---- layer 1 (D=3)
  feat3p_kernel<<<NP / 8, blk256, 0, stream>>>(x, W1, b1, bufA, bufU, pt4);
  knn3_full_kernel<<<B_ * 64, blk256, 0, stream>>>(pt4, cand, cnt);
  selsplit_kernel<<<NP / 4, blk256, 0, stream>>>(cand, cnt, bufA, bufU,
                                                 nullptr, xhi, xlo, sqn);

  // ---- layer 2 (D=128)
  featpart_kernel<<<B_ * 64, blk256, 0, stream>>>(xhi, xlo, vfh2, vfl2, b2,
                                                  bufB, bufU, sqn, tau);
  knn_compact_kernel<<<B_ * 64 * 2, blk128, 0, stream>>>(xhi, xlo, sqn, tau,
                                                         cand, cnt);
  selsplit_kernel<<<NP / 4, blk256, 0, stream>>>(cand, cnt, bufB, bufU,
                                                 nullptr, xhi, xlo, sqn);

  // ---- layer 3 (D=128)
  featpart_kernel<<<B_ * 64, blk256, 0, stream>>>(xhi, xlo, vfh3, vfl3, b3,
                                                  bufB, bufU, sqn, tau);
  knn_compact_kernel<<<B_ * 64 * 2, blk128, 0, stream>>>(xhi, xlo, sqn, tau,
                                                         cand, cnt);
  selsplit_kernel<<<NP / 4, blk256, 0, stream>>>(cand, cnt, bufB, bufU,
                                                 bufA, nullptr, nullptr,
                                                 nullptr);

  // ---- head
  pool_kernel<<<B_ * 64, blk128, 0, stream>>>(bufA, psum);
  head_kernel<<<B_, blk128, 0, stream>>>(psum, W4, b4, W5, b5, out);
}